// Round 1
// baseline (34.389 us; speedup 1.0000x reference)
//
#include <hip/hip_runtime.h>
#include <math.h>

// YOLO-style loss: fused single-pass streaming reduction.
// cells = N*S*S = 8192*169; pred row = 16 f32 (64B, line-aligned); tgt row = 13 f32 (52B, 4B-aligned only).

#define EPSV 1e-6f

__global__ __launch_bounds__(256) void phobia_partial(
    const float* __restrict__ pred, const float* __restrict__ tgt,
    float* __restrict__ ws, long long cells)
{
    long long idx0 = (long long)blockIdx.x * blockDim.x + threadIdx.x;
    long long stride = (long long)gridDim.x * blockDim.x;

    float accA = 0.f;   // sum m * (5*coord + bce_obj + ce)
    float accB = 0.f;   // sum (1-m) * (bce_noobj4 + bce_noobj9)
    float accC = 0.f;   // sum m  (n_obj)

    for (long long i = idx0; i < cells; i += stride) {
        const float* pr = pred + i * 16;
        const float* tr = tgt  + i * 13;

        float4 p03   = *reinterpret_cast<const float4*>(pr);       // 64B-aligned
        float  p4    = pr[4];
        float  p9    = pr[9];
        float2 p1011 = *reinterpret_cast<const float2*>(pr + 10);  // 8B-aligned
        float  p12   = pr[12];

        float t0 = tr[0], t1 = tr[1], t2 = tr[2], t3 = tr[3], t4 = tr[4];
        float t10 = tr[10], t11 = tr[11], t12 = tr[12];

        float m = (t4 > 0.f) ? 1.f : 0.f;

        // coord loss
        float px = 1.f / (1.f + expf(-p03.x));
        float py = 1.f / (1.f + expf(-p03.y));
        float dx = px - t0;
        float dy = py - t1;
        float dw = sqrtf(fabsf(p03.z) + EPSV) - sqrtf(fabsf(t2) + EPSV);
        float dh = sqrtf(fabsf(p03.w) + EPSV) - sqrtf(fabsf(t3) + EPSV);
        float coord = dx*dx + dy*dy + dw*dw + dh*dh;

        // conf (channel 4): share log1p(exp(-|z|)) between logsig(z) and logsig(-z)
        float l1p4 = log1pf(expf(-fabsf(p4)));
        float logsig_p4 = fminf(p4, 0.f) - l1p4;   // log_sigmoid(p4)
        float logsig_m4 = fminf(-p4, 0.f) - l1p4;  // log_sigmoid(-p4)
        float bce_obj = -(t4 * logsig_p4 + (1.f - t4) * logsig_m4);
        float bce_no4 = -logsig_m4;
        // -log_sigmoid(-p9) = max(p9,0) + log1p(exp(-|p9|))
        float bce_no9 = fmaxf(p9, 0.f) + log1pf(expf(-fabsf(p9)));

        // class CE: argmax of one-hot target (first-max semantics), stable LSE
        int tcls = 0; float bt = t10;
        if (t11 > bt) { bt = t11; tcls = 1; }
        if (t12 > bt) { tcls = 2; }
        float lt = (tcls == 0) ? p1011.x : ((tcls == 1) ? p1011.y : p12);
        float mx = fmaxf(p1011.x, fmaxf(p1011.y, p12));
        float lse = mx + logf(expf(p1011.x - mx) + expf(p1011.y - mx) + expf(p12 - mx));
        float ce = lse - lt;

        accA += m * (5.f * coord + bce_obj + ce);
        accB += (1.f - m) * (bce_no4 + bce_no9);
        accC += m;
    }

    // wave64 reduce
    #pragma unroll
    for (int o = 32; o > 0; o >>= 1) {
        accA += __shfl_down(accA, o, 64);
        accB += __shfl_down(accB, o, 64);
        accC += __shfl_down(accC, o, 64);
    }
    __shared__ float sA[4], sB[4], sC[4];
    int wave = threadIdx.x >> 6;
    int lane = threadIdx.x & 63;
    if (lane == 0) { sA[wave] = accA; sB[wave] = accB; sC[wave] = accC; }
    __syncthreads();
    if (threadIdx.x == 0) {
        float A = sA[0] + sA[1] + sA[2] + sA[3];
        float B = sB[0] + sB[1] + sB[2] + sB[3];
        float C = sC[0] + sC[1] + sC[2] + sC[3];
        ws[blockIdx.x * 3 + 0] = A;
        ws[blockIdx.x * 3 + 1] = B;
        ws[blockIdx.x * 3 + 2] = C;
    }
}

__global__ __launch_bounds__(1024) void phobia_final(
    const float* __restrict__ ws, int nblocks, float* __restrict__ out, long long cells)
{
    float a = 0.f, b = 0.f, c = 0.f;
    for (int i = threadIdx.x; i < nblocks; i += 1024) {
        a += ws[i * 3 + 0];
        b += ws[i * 3 + 1];
        c += ws[i * 3 + 2];
    }
    #pragma unroll
    for (int o = 32; o > 0; o >>= 1) {
        a += __shfl_down(a, o, 64);
        b += __shfl_down(b, o, 64);
        c += __shfl_down(c, o, 64);
    }
    __shared__ float sA[16], sB[16], sC[16];
    int wave = threadIdx.x >> 6;
    int lane = threadIdx.x & 63;
    if (lane == 0) { sA[wave] = a; sB[wave] = b; sC[wave] = c; }
    __syncthreads();
    if (threadIdx.x == 0) {
        float A = 0.f, B = 0.f, C = 0.f;
        #pragma unroll
        for (int w = 0; w < 16; ++w) { A += sA[w]; B += sB[w]; C += sC[w]; }
        float batch = (float)(cells / 169);            // N = 8192
        float invb = 1.f / batch;
        float div_obj   = (C > 0.f) ? invb : 1.f;       // n_obj > 0
        float div_noobj = (C < (float)cells) ? invb : 1.f; // n_noobj > 0
        out[0] = A * div_obj + 0.5f * B * div_noobj;
    }
}

extern "C" void kernel_launch(void* const* d_in, const int* in_sizes, int n_in,
                              void* d_out, int out_size, void* d_ws, size_t ws_size,
                              hipStream_t stream) {
    const float* pred = (const float*)d_in[0];
    const float* tgt  = (const float*)d_in[1];
    float* out = (float*)d_out;
    float* ws  = (float*)d_ws;

    long long cells = (long long)in_sizes[0] / 16;  // 8192*13*13

    int blocks = 1024;
    size_t need = (size_t)blocks * 3 * sizeof(float);
    while (need > ws_size && blocks > 1) { blocks >>= 1; need = (size_t)blocks * 3 * sizeof(float); }

    phobia_partial<<<blocks, 256, 0, stream>>>(pred, tgt, ws, cells);
    phobia_final<<<1, 1024, 0, stream>>>(ws, blocks, out, cells);
}